// Round 2
// baseline (1991.669 us; speedup 1.0000x reference)
//
#include <hip/hip_runtime.h>

#define E_DIM 1024
#define H_DIM 16
#define T_DIM 2048
#define B_DIM 2
#define HD_DIM 64
#define NROWS (T_DIM*B_DIM)   // 4096

typedef unsigned short u16;
typedef unsigned long long u64;
typedef __attribute__((ext_vector_type(8))) short bf16x8;
typedef __attribute__((ext_vector_type(4))) float f32x4;

__device__ __forceinline__ u16 f2bf(float f){
  unsigned int u = __float_as_uint(f);
  u = u + 0x7fffu + ((u>>16)&1u);      // round-to-nearest-even
  return (u16)(u>>16);
}

// async global->LDS, 16B per lane. Dest must be linear base + lane*16.
__device__ __forceinline__ void gl_lds16(const u16* g, u16* l){
  __builtin_amdgcn_global_load_lds(
      (const __attribute__((address_space(1))) void*)g,
      (__attribute__((address_space(3))) void*)l, 16, 0, 0);
}

// 16-lane butterfly reduction via DPP (pure VALU, no LDS pipe).
#define DPP_F(v, op, ctrl) \
  v = op(v, __int_as_float(__builtin_amdgcn_mov_dpp(__float_as_int(v), ctrl, 0xf, 0xf, true)))
__device__ __forceinline__ float fadd_(float a, float b){ return a + b; }

// ---------------- fp32 -> bf16 conversion (4 elems/thread) ----------------
__global__ __launch_bounds__(256) void convert_f32_bf16(
    const float* __restrict__ src, u16* __restrict__ dst, int n4)
{
  int i = blockIdx.x*256 + threadIdx.x;
  if (i < n4){
    float4 f = ((const float4*)src)[i];
    u64 pack =  (u64)f2bf(f.x)
             | ((u64)f2bf(f.y) << 16)
             | ((u64)f2bf(f.z) << 32)
             | ((u64)f2bf(f.w) << 48);
    ((u64*)dst)[i] = pack;
  }
}

// ---------------- fused QKV projection GEMM -------------------------------
// m97 structure: 128x128 tile, LDS-staged via global_load_lds width 16,
// BK=32, 4 waves x (64x64), 2 barriers per k-step. XCD-swizzled block id.
__global__ __launch_bounds__(256) void gemm_qkv(
    const u16* __restrict__ xb, const u16* __restrict__ wb,
    const float* __restrict__ bq, const float* __restrict__ bk,
    const float* __restrict__ bv,
    u16* __restrict__ qb, u16* __restrict__ kb, u16* __restrict__ vtb)
{
  __shared__ u16 sA[128*32];
  __shared__ u16 sB[128*32];
  int tid = threadIdx.x;
  int w = tid >> 6, lane = tid & 63;
  int qd = lane >> 4, l15 = lane & 15;
  int wr = w >> 1, wc = w & 1;

  // XCD-aware bijective swizzle: nwg = 24*32 = 768, 768 % 8 == 0.
  unsigned bid = blockIdx.y * 24u + blockIdx.x;
  unsigned swz = (bid & 7u) * 96u + (bid >> 3);
  int bx = (int)(swz % 24u);
  int by = (int)(swz / 24u);
  int row0 = by*128;
  int col0 = bx*128;

  int srow = tid >> 2;
  int scol = (tid & 3) * 8;
  const u16* ga0 = xb + (size_t)(row0 + srow)*E_DIM + scol;
  const u16* ga1 = xb + (size_t)(row0 + 64 + srow)*E_DIM + scol;
  const u16* gb0 = wb + (size_t)(col0 + srow)*E_DIM + scol;
  const u16* gb1 = wb + (size_t)(col0 + 64 + srow)*E_DIM + scol;
  u16* lA0 = sA + tid*8;
  u16* lA1 = sA + 2048 + tid*8;
  u16* lB0 = sB + tid*8;
  u16* lB1 = sB + 2048 + tid*8;

  f32x4 z = {0.f,0.f,0.f,0.f};
  f32x4 acc[4][4];
  for (int i=0;i<4;i++) for (int j=0;j<4;j++) acc[i][j] = z;

  const u16* pa = sA + (wr*64 + l15)*32 + qd*8;
  const u16* pb = sB + (wc*64 + l15)*32 + qd*8;

  for (int kk = 0; kk < E_DIM; kk += 32){
    gl_lds16(ga0 + kk, lA0);
    gl_lds16(ga1 + kk, lA1);
    gl_lds16(gb0 + kk, lB0);
    gl_lds16(gb1 + kk, lB1);
    __syncthreads();
    bf16x8 a[4], bfr[4];
#pragma unroll
    for (int i=0;i<4;i++){
      a[i]   = *(const bf16x8*)(pa + i*512);
      bfr[i] = *(const bf16x8*)(pb + i*512);
    }
#pragma unroll
    for (int i=0;i<4;i++)
#pragma unroll
      for (int j=0;j<4;j++)
        acc[i][j] = __builtin_amdgcn_mfma_f32_16x16x32_bf16(a[i], bfr[j], acc[i][j], 0,0,0);
    __syncthreads();
  }

#pragma unroll
  for (int j=0;j<4;j++){
    int n = col0 + wc*64 + j*16 + l15;
    int p = n >> 10;          // 0=q 1=k 2=v
    int e = n & 1023;
    int hh = e >> 6, d = e & 63;
    float bias = (p==0) ? bq[e] : (p==1) ? bk[e] : bv[e];
#pragma unroll
    for (int i=0;i<4;i++){
#pragma unroll
      for (int r=0;r<4;r++){
        int row = row0 + wr*64 + i*16 + qd*4 + r;
        int t = row >> 1, b = row & 1;
        float val = acc[i][j][r] + bias;
        if (p == 0){
          val *= 0.125f;
          qb[((size_t)((b*H_DIM+hh)*T_DIM + t))*HD_DIM + d] = f2bf(val);
        } else if (p == 1){
          kb[((size_t)((b*H_DIM+hh)*T_DIM + t))*HD_DIM + d] = f2bf(val);
        } else {
          vtb[((size_t)((b*H_DIM+hh)*HD_DIM + d))*T_DIM + t] = f2bf(val);
        }
      }
    }
  }
}

// ---------------- flash attention ----------------------------------------
// One block = one (b,h) x 64 t-rows. 8 waves (512 thr): 4 t-groups x 2 s-halves.
// Each wave runs 32 s-steps over its half; pairs merge (m,l,o) via LDS at end.
__global__ __launch_bounds__(512, 8) void attn_kernel(
    const u16* __restrict__ qb, const u16* __restrict__ kb,
    const u16* __restrict__ vtb, const float* __restrict__ bias,
    const void* __restrict__ pmask, u16* __restrict__ attnb)
{
  __shared__ u16 p_lds[8][16][32];     // 8 KB
  __shared__ float c_o[4][64][16];     // 16 KB
  __shared__ float c_ml[4][64][8];     // 8 KB
  __shared__ int s_bytemode;
  int tid = threadIdx.x;
  if (tid == 0) s_bytemode = 0;
  __syncthreads();
  {
    // detect mask dtype: int32 {0,1} has zero bytes at offset%4 != 0
    const unsigned char* pb_ = (const unsigned char*)pmask;
    unsigned char c = pb_[tid*4+1] | pb_[tid*4+2] | pb_[tid*4+3];
    if (c) s_bytemode = 1;    // benign same-value race
  }
  __syncthreads();
  int bytemode = s_bytemode;

  int wid = tid >> 6, lane = tid & 63;
  int pair = wid & 3, shalf = wid >> 2;
  int qd = lane >> 4, l15 = lane & 15;
  int bh = blockIdx.y;
  int b = bh >> 4;            // H=16
  int hh = bh & 15;
  int trow0 = blockIdx.x*64 + pair*16;
  int sbeg = shalf * (T_DIM/2);
  int send = sbeg + (T_DIM/2);

  const u16* qh = qb + (size_t)bh * T_DIM * HD_DIM;
  const u16* kh = kb + (size_t)bh * T_DIM * HD_DIM;
  const u16* vh = vtb + (size_t)bh * HD_DIM * T_DIM;
  const float* biash = bias + (size_t)bh * T_DIM * T_DIM;
  const int* pmi = (const int*)pmask;
  const unsigned char* pmb = (const unsigned char*)pmask;

  int tq = trow0 + l15;
  bf16x8 aq0 = *(const bf16x8*)(qh + (size_t)tq*HD_DIM + qd*8);
  bf16x8 aq1 = *(const bf16x8*)(qh + (size_t)tq*HD_DIM + 32 + qd*8);

  f32x4 z = {0.f,0.f,0.f,0.f};
  f32x4 o[4]; for (int i=0;i<4;i++) o[i] = z;
  float m_r[4] = {-1e30f,-1e30f,-1e30f,-1e30f};
  float l_r[4] = {0.f,0.f,0.f,0.f};

  int trq = trow0 + qd*4;

  // prologue: load first-step K fragments + bias
  bf16x8 k00 = *(const bf16x8*)(kh + (size_t)(sbeg+l15)*HD_DIM + qd*8);
  bf16x8 k01 = *(const bf16x8*)(kh + (size_t)(sbeg+l15)*HD_DIM + 32 + qd*8);
  bf16x8 k10 = *(const bf16x8*)(kh + (size_t)(sbeg+16+l15)*HD_DIM + qd*8);
  bf16x8 k11 = *(const bf16x8*)(kh + (size_t)(sbeg+16+l15)*HD_DIM + 32 + qd*8);
  float pb0[4], pb1[4];
#pragma unroll
  for (int r=0;r<4;r++){
    pb0[r] = biash[(size_t)(trq+r)*T_DIM + sbeg + l15];
    pb1[r] = biash[(size_t)(trq+r)*T_DIM + sbeg + 16 + l15];
  }

  for (int s0 = sbeg; s0 < send; s0 += 32){
    // issue next-step prefetches first (wrap on last iter; values unused)
    int sn = (s0 + 32 < send) ? (s0 + 32) : sbeg;
    bf16x8 nk00 = *(const bf16x8*)(kh + (size_t)(sn+l15)*HD_DIM + qd*8);
    bf16x8 nk01 = *(const bf16x8*)(kh + (size_t)(sn+l15)*HD_DIM + 32 + qd*8);
    bf16x8 nk10 = *(const bf16x8*)(kh + (size_t)(sn+16+l15)*HD_DIM + qd*8);
    bf16x8 nk11 = *(const bf16x8*)(kh + (size_t)(sn+16+l15)*HD_DIM + 32 + qd*8);
    float nb0[4], nb1[4];
#pragma unroll
    for (int r=0;r<4;r++){
      nb0[r] = biash[(size_t)(trq+r)*T_DIM + sn + l15];
      nb1[r] = biash[(size_t)(trq+r)*T_DIM + sn + 16 + l15];
    }

    int sc0 = s0 + l15, sc1 = s0 + 16 + l15;
    bool msk0 = bytemode ? (pmb[b*T_DIM + sc0] != 0) : (pmi[b*T_DIM + sc0] != 0);
    bool msk1 = bytemode ? (pmb[b*T_DIM + sc1] != 0) : (pmi[b*T_DIM + sc1] != 0);

    f32x4 sA = __builtin_amdgcn_mfma_f32_16x16x32_bf16(aq1, k01, z, 0,0,0);
    sA       = __builtin_amdgcn_mfma_f32_16x16x32_bf16(aq0, k00, sA, 0,0,0);
    f32x4 sB = __builtin_amdgcn_mfma_f32_16x16x32_bf16(aq1, k11, z, 0,0,0);
    sB       = __builtin_amdgcn_mfma_f32_16x16x32_bf16(aq0, k10, sB, 0,0,0);

#pragma unroll
    for (int r=0;r<4;r++){
      float v0 = (msk0 ? -1e-16f : sA[r]) + pb0[r];
      float v1 = (msk1 ? -1e-16f : sB[r]) + pb1[r];
      float tm = fmaxf(v0, v1);
      DPP_F(tm, fmaxf, 0xB1);
      DPP_F(tm, fmaxf, 0x4E);
      DPP_F(tm, fmaxf, 0x141);
      DPP_F(tm, fmaxf, 0x140);
      float mn = fmaxf(m_r[r], tm);
      float alpha = __expf(m_r[r] - mn);
      float p0 = __expf(v0 - mn);
      float p1 = __expf(v1 - mn);
      float rs = p0 + p1;
      DPP_F(rs, fadd_, 0xB1);
      DPP_F(rs, fadd_, 0x4E);
      DPP_F(rs, fadd_, 0x141);
      DPP_F(rs, fadd_, 0x140);
      l_r[r] = l_r[r]*alpha + rs;
      m_r[r] = mn;
      o[0][r] *= alpha; o[1][r] *= alpha; o[2][r] *= alpha; o[3][r] *= alpha;
      p_lds[wid][qd*4+r][l15]      = f2bf(p0);
      p_lds[wid][qd*4+r][16 + l15] = f2bf(p1);
    }
    // wave-local ordering of p_lds write->read; does NOT drain vmcnt.
    __asm__ __volatile__("s_waitcnt lgkmcnt(0)" ::: "memory");

    bf16x8 ap = *(const bf16x8*)(&p_lds[wid][l15][qd*8]);
#pragma unroll
    for (int dt=0; dt<4; dt++){
      bf16x8 bv = *(const bf16x8*)(vh + (size_t)(dt*16 + l15)*T_DIM + s0 + qd*8);
      o[dt] = __builtin_amdgcn_mfma_f32_16x16x32_bf16(ap, bv, o[dt], 0,0,0);
    }

    // rotate prefetched state
    k00 = nk00; k01 = nk01; k10 = nk10; k11 = nk11;
#pragma unroll
    for (int r=0;r<4;r++){ pb0[r] = nb0[r]; pb1[r] = nb1[r]; }
  }

  // -------- cross-wave merge of the two s-halves --------
  if (shalf == 1){
#pragma unroll
    for (int r=0;r<4;r++){
      c_ml[pair][lane][r]   = m_r[r];
      c_ml[pair][lane][4+r] = l_r[r];
#pragma unroll
      for (int dt=0;dt<4;dt++) c_o[pair][lane][dt*4+r] = o[dt][r];
    }
  }
  __syncthreads();
  if (shalf == 0){
#pragma unroll
    for (int r=0;r<4;r++){
      float m2 = c_ml[pair][lane][r];
      float l2 = c_ml[pair][lane][4+r];
      float mn = fmaxf(m_r[r], m2);
      float a1 = __expf(m_r[r] - mn);
      float a2 = __expf(m2 - mn);
      float lt = l_r[r]*a1 + l2*a2;
      int t = trow0 + qd*4 + r;
#pragma unroll
      for (int dt=0;dt<4;dt++){
        float val = (o[dt][r]*a1 + c_o[pair][lane][dt*4+r]*a2) / lt;
        attnb[(size_t)(t*B_DIM + b)*E_DIM + hh*HD_DIM + dt*16 + l15] = f2bf(val);
      }
    }
  }
}

// ---------------- output projection GEMM ----------------------------------
// 128x64 tile (rows x cols) -> grid 16x32 = 512 blocks = 2/CU (was 1/CU).
__global__ __launch_bounds__(256) void gemm_out(
    const u16* __restrict__ ab, const u16* __restrict__ wob,
    const float* __restrict__ bo, float* __restrict__ out)
{
  __shared__ u16 sA[128*32];   // 8 KB
  __shared__ u16 sB[64*32];    // 4 KB
  int tid = threadIdx.x;
  int w = tid >> 6, lane = tid & 63;
  int qd = lane >> 4, l15 = lane & 15;
  int wr = w >> 1, wc = w & 1;    // wr: 64-row half, wc: 32-col half

  // XCD swizzle: nwg = 16*32 = 512, %8==0.
  unsigned bid = blockIdx.y * 16u + blockIdx.x;
  unsigned swz = (bid & 7u) * 64u + (bid >> 3);
  int bx = (int)(swz % 16u);
  int by = (int)(swz / 16u);
  int row0 = by*128;
  int col0 = bx*64;

  int srow = tid >> 2;
  int scol = (tid & 3) * 8;
  const u16* ga0 = ab + (size_t)(row0 + srow)*E_DIM + scol;
  const u16* ga1 = ab + (size_t)(row0 + 64 + srow)*E_DIM + scol;
  const u16* gb0 = wob + (size_t)(col0 + srow)*E_DIM + scol;
  u16* lA0 = sA + tid*8;
  u16* lA1 = sA + 2048 + tid*8;
  u16* lB0 = sB + tid*8;

  f32x4 z = {0.f,0.f,0.f,0.f};
  f32x4 acc[4][2];
  for (int i=0;i<4;i++) for (int j=0;j<2;j++) acc[i][j] = z;

  const u16* pa = sA + (wr*64 + l15)*32 + qd*8;
  const u16* pb = sB + (wc*32 + l15)*32 + qd*8;

  for (int kk = 0; kk < E_DIM; kk += 32){
    gl_lds16(ga0 + kk, lA0);
    gl_lds16(ga1 + kk, lA1);
    gl_lds16(gb0 + kk, lB0);
    __syncthreads();
    bf16x8 a[4], bfr[2];
#pragma unroll
    for (int i=0;i<4;i++) a[i] = *(const bf16x8*)(pa + i*512);
#pragma unroll
    for (int j=0;j<2;j++) bfr[j] = *(const bf16x8*)(pb + j*512);
#pragma unroll
    for (int i=0;i<4;i++)
#pragma unroll
      for (int j=0;j<2;j++)
        acc[i][j] = __builtin_amdgcn_mfma_f32_16x16x32_bf16(a[i], bfr[j], acc[i][j], 0,0,0);
    __syncthreads();
  }

#pragma unroll
  for (int j=0;j<2;j++){
    int n = col0 + wc*32 + j*16 + l15;
    float bias = bo[n];
#pragma unroll
    for (int i=0;i<4;i++){
#pragma unroll
      for (int r=0;r<4;r++){
        int row = row0 + wr*64 + i*16 + qd*4 + r;
        out[(size_t)row*E_DIM + n] = acc[i][j][r] + bias;
      }
    }
  }
}

extern "C" void kernel_launch(void* const* d_in, const int* in_sizes, int n_in,
                              void* d_out, int out_size, void* d_ws, size_t ws_size,
                              hipStream_t stream) {
  const float* x    = (const float*)d_in[0];
  const void*  pm   = d_in[1];
  const float* abias= (const float*)d_in[2];
  const float* Wq   = (const float*)d_in[3];
  const float* bq   = (const float*)d_in[4];
  const float* Wk   = (const float*)d_in[5];
  const float* bk   = (const float*)d_in[6];
  const float* Wv   = (const float*)d_in[7];
  const float* bv   = (const float*)d_in[8];
  const float* Wo   = (const float*)d_in[9];
  const float* bo   = (const float*)d_in[10];
  float* out = (float*)d_out;

  char* ws = (char*)d_ws;
  u16* xb    = (u16*)(ws);                      // 8 MB  [4096][1024]
  u16* wqkvb = (u16*)(ws + (8u<<20));           // 6 MB  [3072][1024] (wq|wk|wv)
  u16* wob   = (u16*)(ws + (14u<<20));          // 2 MB  [1024][1024]
  u16* qb    = (u16*)(ws + (16u<<20));          // 8 MB  [b][h][t][d]
  u16* kb    = (u16*)(ws + (24u<<20));          // 8 MB  [b][h][t][d]
  u16* vtb   = (u16*)(ws + (32u<<20));          // 8 MB  [b][h][d][t]
  u16* attnb = (u16*)(ws + (40u<<20));          // 8 MB  [4096][1024]

  // converts
  {
    int n4x = (T_DIM*B_DIM*E_DIM)/4;            // 1048576
    convert_f32_bf16<<<dim3(n4x/256), 256, 0, stream>>>(x, xb, n4x);
    int n4w = (E_DIM*E_DIM)/4;                  // 262144
    convert_f32_bf16<<<dim3(n4w/256), 256, 0, stream>>>(Wq, wqkvb,                 n4w);
    convert_f32_bf16<<<dim3(n4w/256), 256, 0, stream>>>(Wk, wqkvb + (1u<<20),      n4w);
    convert_f32_bf16<<<dim3(n4w/256), 256, 0, stream>>>(Wv, wqkvb + (2u<<20),      n4w);
    convert_f32_bf16<<<dim3(n4w/256), 256, 0, stream>>>(Wo, wob,                   n4w);
  }

  gemm_qkv<<<dim3(3*E_DIM/128, NROWS/128), 256, 0, stream>>>(
      xb, wqkvb, bq, bk, bv, qb, kb, vtb);

  attn_kernel<<<dim3(T_DIM/64, B_DIM*H_DIM), 512, 0, stream>>>(
      qb, kb, vtb, abias, pm, attnb);

  gemm_out<<<dim3(E_DIM/64, NROWS/128), 256, 0, stream>>>(
      attnb, wob, bo, out);
}

// Round 3
// 954.379 us; speedup vs baseline: 2.0869x; 2.0869x over previous
//
#include <hip/hip_runtime.h>

#define E_DIM 1024
#define H_DIM 16
#define T_DIM 2048
#define B_DIM 2
#define HD_DIM 64
#define NROWS (T_DIM*B_DIM)   // 4096

typedef unsigned short u16;
typedef unsigned long long u64;
typedef __attribute__((ext_vector_type(8))) short bf16x8;
typedef __attribute__((ext_vector_type(4))) float f32x4;

__device__ __forceinline__ u16 f2bf(float f){
  unsigned int u = __float_as_uint(f);
  u = u + 0x7fffu + ((u>>16)&1u);      // round-to-nearest-even
  return (u16)(u>>16);
}

// async global->LDS, 16B per lane. Dest must be linear base + lane*16.
__device__ __forceinline__ void gl_lds16(const u16* g, u16* l){
  __builtin_amdgcn_global_load_lds(
      (const __attribute__((address_space(1))) void*)g,
      (__attribute__((address_space(3))) void*)l, 16, 0, 0);
}

// 16-lane butterfly reduction via DPP (pure VALU, no LDS pipe).
#define DPP_F(v, op, ctrl) \
  v = op(v, __int_as_float(__builtin_amdgcn_mov_dpp(__float_as_int(v), ctrl, 0xf, 0xf, true)))
__device__ __forceinline__ float fadd_(float a, float b){ return a + b; }

// ---------------- fp32 -> bf16 conversion (4 elems/thread) ----------------
__global__ __launch_bounds__(256) void convert_f32_bf16(
    const float* __restrict__ src, u16* __restrict__ dst, int n4)
{
  int i = blockIdx.x*256 + threadIdx.x;
  if (i < n4){
    float4 f = ((const float4*)src)[i];
    u64 pack =  (u64)f2bf(f.x)
             | ((u64)f2bf(f.y) << 16)
             | ((u64)f2bf(f.z) << 32)
             | ((u64)f2bf(f.w) << 48);
    ((u64*)dst)[i] = pack;
  }
}

// ---------------- fused QKV projection GEMM -------------------------------
// m97 structure: 128x128 tile, LDS-staged via global_load_lds width 16,
// BK=32, 4 waves x (64x64), 2 barriers per k-step. XCD-swizzled block id.
__global__ __launch_bounds__(256) void gemm_qkv(
    const u16* __restrict__ xb, const u16* __restrict__ wb,
    const float* __restrict__ bq, const float* __restrict__ bk,
    const float* __restrict__ bv,
    u16* __restrict__ qb, u16* __restrict__ kb, u16* __restrict__ vtb)
{
  __shared__ u16 sA[128*32];
  __shared__ u16 sB[128*32];
  int tid = threadIdx.x;
  int w = tid >> 6, lane = tid & 63;
  int qd = lane >> 4, l15 = lane & 15;
  int wr = w >> 1, wc = w & 1;

  // XCD-aware bijective swizzle: nwg = 24*32 = 768, 768 % 8 == 0.
  unsigned bid = blockIdx.y * 24u + blockIdx.x;
  unsigned swz = (bid & 7u) * 96u + (bid >> 3);
  int bx = (int)(swz % 24u);
  int by = (int)(swz / 24u);
  int row0 = by*128;
  int col0 = bx*128;

  int srow = tid >> 2;
  int scol = (tid & 3) * 8;
  const u16* ga0 = xb + (size_t)(row0 + srow)*E_DIM + scol;
  const u16* ga1 = xb + (size_t)(row0 + 64 + srow)*E_DIM + scol;
  const u16* gb0 = wb + (size_t)(col0 + srow)*E_DIM + scol;
  const u16* gb1 = wb + (size_t)(col0 + 64 + srow)*E_DIM + scol;
  u16* lA0 = sA + tid*8;
  u16* lA1 = sA + 2048 + tid*8;
  u16* lB0 = sB + tid*8;
  u16* lB1 = sB + 2048 + tid*8;

  f32x4 z = {0.f,0.f,0.f,0.f};
  f32x4 acc[4][4];
  for (int i=0;i<4;i++) for (int j=0;j<4;j++) acc[i][j] = z;

  const u16* pa = sA + (wr*64 + l15)*32 + qd*8;
  const u16* pb = sB + (wc*64 + l15)*32 + qd*8;

  for (int kk = 0; kk < E_DIM; kk += 32){
    gl_lds16(ga0 + kk, lA0);
    gl_lds16(ga1 + kk, lA1);
    gl_lds16(gb0 + kk, lB0);
    gl_lds16(gb1 + kk, lB1);
    __syncthreads();
    bf16x8 a[4], bfr[4];
#pragma unroll
    for (int i=0;i<4;i++){
      a[i]   = *(const bf16x8*)(pa + i*512);
      bfr[i] = *(const bf16x8*)(pb + i*512);
    }
#pragma unroll
    for (int i=0;i<4;i++)
#pragma unroll
      for (int j=0;j<4;j++)
        acc[i][j] = __builtin_amdgcn_mfma_f32_16x16x32_bf16(a[i], bfr[j], acc[i][j], 0,0,0);
    __syncthreads();
  }

#pragma unroll
  for (int j=0;j<4;j++){
    int n = col0 + wc*64 + j*16 + l15;
    int p = n >> 10;          // 0=q 1=k 2=v
    int e = n & 1023;
    int hh = e >> 6, d = e & 63;
    float bias = (p==0) ? bq[e] : (p==1) ? bk[e] : bv[e];
#pragma unroll
    for (int i=0;i<4;i++){
#pragma unroll
      for (int r=0;r<4;r++){
        int row = row0 + wr*64 + i*16 + qd*4 + r;
        int t = row >> 1, b = row & 1;
        float val = acc[i][j][r] + bias;
        if (p == 0){
          val *= 0.125f;
          qb[((size_t)((b*H_DIM+hh)*T_DIM + t))*HD_DIM + d] = f2bf(val);
        } else if (p == 1){
          kb[((size_t)((b*H_DIM+hh)*T_DIM + t))*HD_DIM + d] = f2bf(val);
        } else {
          vtb[((size_t)((b*H_DIM+hh)*HD_DIM + d))*T_DIM + t] = f2bf(val);
        }
      }
    }
  }
}

// ---------------- flash attention ----------------------------------------
// One block = one (b,h) x 64 t-rows. 8 waves (512 thr): 4 t-groups x 2 s-halves.
// launch_bounds (512,4): VGPR cap 128 -- round 2's (512,8) capped at 32 and
// spilled 4.5 GB of scratch per dispatch. Do not lower the cap below ~110.
// Bias (the only HBM stream) prefetched 2 steps deep; K 1 step; V issued
// early so its L2 latency hides under the softmax chain.
__global__ __launch_bounds__(512, 4) void attn_kernel(
    const u16* __restrict__ qb, const u16* __restrict__ kb,
    const u16* __restrict__ vtb, const float* __restrict__ bias,
    const void* __restrict__ pmask, u16* __restrict__ attnb)
{
  __shared__ u16 p_lds[8][16][32];     // 8 KB
  __shared__ float c_o[4][64][16];     // 16 KB
  __shared__ float c_ml[4][64][8];     // 8 KB
  __shared__ int s_bytemode;
  int tid = threadIdx.x;
  if (tid == 0) s_bytemode = 0;
  __syncthreads();
  {
    // detect mask dtype: int32 {0,1} has zero bytes at offset%4 != 0
    const unsigned char* pb_ = (const unsigned char*)pmask;
    unsigned char c = pb_[tid*4+1] | pb_[tid*4+2] | pb_[tid*4+3];
    if (c) s_bytemode = 1;    // benign same-value race
  }
  __syncthreads();
  int bytemode = s_bytemode;

  int wid = tid >> 6, lane = tid & 63;
  int pair = wid & 3, shalf = wid >> 2;
  int qd = lane >> 4, l15 = lane & 15;
  int bh = blockIdx.y;
  int b = bh >> 4;            // H=16
  int hh = bh & 15;
  int trow0 = blockIdx.x*64 + pair*16;
  int sbeg = shalf * (T_DIM/2);
  int send = sbeg + (T_DIM/2);

  const u16* qh = qb + (size_t)bh * T_DIM * HD_DIM;
  const u16* kh = kb + (size_t)bh * T_DIM * HD_DIM;
  const u16* vh = vtb + (size_t)bh * HD_DIM * T_DIM;
  const float* biash = bias + (size_t)bh * T_DIM * T_DIM;
  const int* pmi = (const int*)pmask;
  const unsigned char* pmb = (const unsigned char*)pmask;

  int tq = trow0 + l15;
  bf16x8 aq0 = *(const bf16x8*)(qh + (size_t)tq*HD_DIM + qd*8);
  bf16x8 aq1 = *(const bf16x8*)(qh + (size_t)tq*HD_DIM + 32 + qd*8);

  f32x4 z = {0.f,0.f,0.f,0.f};
  f32x4 o[4]; for (int i=0;i<4;i++) o[i] = z;
  float m_r[4] = {-1e30f,-1e30f,-1e30f,-1e30f};
  float l_r[4] = {0.f,0.f,0.f,0.f};

  int trq = trow0 + qd*4;

  // prologue: K frags for step 0; bias for steps 0 and 1 (depth-2 pipeline)
  bf16x8 k00 = *(const bf16x8*)(kh + (size_t)(sbeg+l15)*HD_DIM + qd*8);
  bf16x8 k01 = *(const bf16x8*)(kh + (size_t)(sbeg+l15)*HD_DIM + 32 + qd*8);
  bf16x8 k10 = *(const bf16x8*)(kh + (size_t)(sbeg+16+l15)*HD_DIM + qd*8);
  bf16x8 k11 = *(const bf16x8*)(kh + (size_t)(sbeg+16+l15)*HD_DIM + 32 + qd*8);
  float pbA0[4], pbA1[4], pbB0[4], pbB1[4];
#pragma unroll
  for (int r=0;r<4;r++){
    pbA0[r] = biash[(size_t)(trq+r)*T_DIM + sbeg + l15];
    pbA1[r] = biash[(size_t)(trq+r)*T_DIM + sbeg + 16 + l15];
    pbB0[r] = biash[(size_t)(trq+r)*T_DIM + sbeg + 32 + l15];
    pbB1[r] = biash[(size_t)(trq+r)*T_DIM + sbeg + 48 + l15];
  }

  for (int s0 = sbeg; s0 < send; s0 += 32){
    int sn  = (s0 + 32 < send) ? (s0 + 32) : sbeg;   // K prefetch (depth 1)
    int sn2 = (s0 + 64 < send) ? (s0 + 64) : sbeg;   // bias prefetch (depth 2)

    // issue bias depth-2 prefetch first (HBM stream, longest latency)
    float nb0[4], nb1[4];
#pragma unroll
    for (int r=0;r<4;r++){
      nb0[r] = biash[(size_t)(trq+r)*T_DIM + sn2 + l15];
      nb1[r] = biash[(size_t)(trq+r)*T_DIM + sn2 + 16 + l15];
    }
    // K prefetch for next step (L2-resident)
    bf16x8 nk00 = *(const bf16x8*)(kh + (size_t)(sn+l15)*HD_DIM + qd*8);
    bf16x8 nk01 = *(const bf16x8*)(kh + (size_t)(sn+l15)*HD_DIM + 32 + qd*8);
    bf16x8 nk10 = *(const bf16x8*)(kh + (size_t)(sn+16+l15)*HD_DIM + qd*8);
    bf16x8 nk11 = *(const bf16x8*)(kh + (size_t)(sn+16+l15)*HD_DIM + 32 + qd*8);

    int sc0 = s0 + l15, sc1 = s0 + 16 + l15;
    bool msk0 = bytemode ? (pmb[b*T_DIM + sc0] != 0) : (pmi[b*T_DIM + sc0] != 0);
    bool msk1 = bytemode ? (pmb[b*T_DIM + sc1] != 0) : (pmi[b*T_DIM + sc1] != 0);

    f32x4 sA = __builtin_amdgcn_mfma_f32_16x16x32_bf16(aq1, k01, z, 0,0,0);
    sA       = __builtin_amdgcn_mfma_f32_16x16x32_bf16(aq0, k00, sA, 0,0,0);
    f32x4 sB = __builtin_amdgcn_mfma_f32_16x16x32_bf16(aq1, k11, z, 0,0,0);
    sB       = __builtin_amdgcn_mfma_f32_16x16x32_bf16(aq0, k10, sB, 0,0,0);

    // early-issue V loads for the CURRENT step: L2 latency hides under softmax
    bf16x8 bv0 = *(const bf16x8*)(vh + (size_t)(     l15)*T_DIM + s0 + qd*8);
    bf16x8 bv1 = *(const bf16x8*)(vh + (size_t)(16 + l15)*T_DIM + s0 + qd*8);
    bf16x8 bv2 = *(const bf16x8*)(vh + (size_t)(32 + l15)*T_DIM + s0 + qd*8);
    bf16x8 bv3 = *(const bf16x8*)(vh + (size_t)(48 + l15)*T_DIM + s0 + qd*8);

#pragma unroll
    for (int r=0;r<4;r++){
      float v0 = (msk0 ? -1e-16f : sA[r]) + pbA0[r];
      float v1 = (msk1 ? -1e-16f : sB[r]) + pbA1[r];
      float tm = fmaxf(v0, v1);
      DPP_F(tm, fmaxf, 0xB1);
      DPP_F(tm, fmaxf, 0x4E);
      DPP_F(tm, fmaxf, 0x141);
      DPP_F(tm, fmaxf, 0x140);
      float mn = fmaxf(m_r[r], tm);
      float alpha = __expf(m_r[r] - mn);
      float p0 = __expf(v0 - mn);
      float p1 = __expf(v1 - mn);
      float rs = p0 + p1;
      DPP_F(rs, fadd_, 0xB1);
      DPP_F(rs, fadd_, 0x4E);
      DPP_F(rs, fadd_, 0x141);
      DPP_F(rs, fadd_, 0x140);
      l_r[r] = l_r[r]*alpha + rs;
      m_r[r] = mn;
      o[0][r] *= alpha; o[1][r] *= alpha; o[2][r] *= alpha; o[3][r] *= alpha;
      p_lds[wid][qd*4+r][l15]      = f2bf(p0);
      p_lds[wid][qd*4+r][16 + l15] = f2bf(p1);
    }
    // wave-local ordering of p_lds write->read; does NOT drain vmcnt.
    __asm__ __volatile__("s_waitcnt lgkmcnt(0)" ::: "memory");

    bf16x8 ap = *(const bf16x8*)(&p_lds[wid][l15][qd*8]);
    o[0] = __builtin_amdgcn_mfma_f32_16x16x32_bf16(ap, bv0, o[0], 0,0,0);
    o[1] = __builtin_amdgcn_mfma_f32_16x16x32_bf16(ap, bv1, o[1], 0,0,0);
    o[2] = __builtin_amdgcn_mfma_f32_16x16x32_bf16(ap, bv2, o[2], 0,0,0);
    o[3] = __builtin_amdgcn_mfma_f32_16x16x32_bf16(ap, bv3, o[3], 0,0,0);

    // rotate pipeline state
    k00 = nk00; k01 = nk01; k10 = nk10; k11 = nk11;
#pragma unroll
    for (int r=0;r<4;r++){
      pbA0[r] = pbB0[r]; pbA1[r] = pbB1[r];
      pbB0[r] = nb0[r];  pbB1[r] = nb1[r];
    }
  }

  // -------- cross-wave merge of the two s-halves --------
  if (shalf == 1){
#pragma unroll
    for (int r=0;r<4;r++){
      c_ml[pair][lane][r]   = m_r[r];
      c_ml[pair][lane][4+r] = l_r[r];
#pragma unroll
      for (int dt=0;dt<4;dt++) c_o[pair][lane][dt*4+r] = o[dt][r];
    }
  }
  __syncthreads();
  if (shalf == 0){
#pragma unroll
    for (int r=0;r<4;r++){
      float m2 = c_ml[pair][lane][r];
      float l2 = c_ml[pair][lane][4+r];
      float mn = fmaxf(m_r[r], m2);
      float a1 = __expf(m_r[r] - mn);
      float a2 = __expf(m2 - mn);
      float lt = l_r[r]*a1 + l2*a2;
      int t = trow0 + qd*4 + r;
#pragma unroll
      for (int dt=0;dt<4;dt++){
        float val = (o[dt][r]*a1 + c_o[pair][lane][dt*4+r]*a2) / lt;
        attnb[(size_t)(t*B_DIM + b)*E_DIM + hh*HD_DIM + dt*16 + l15] = f2bf(val);
      }
    }
  }
}

// ---------------- output projection GEMM ----------------------------------
// 128x64 tile (rows x cols) -> grid 16x32 = 512 blocks = 2/CU.
__global__ __launch_bounds__(256) void gemm_out(
    const u16* __restrict__ ab, const u16* __restrict__ wob,
    const float* __restrict__ bo, float* __restrict__ out)
{
  __shared__ u16 sA[128*32];   // 8 KB
  __shared__ u16 sB[64*32];    // 4 KB
  int tid = threadIdx.x;
  int w = tid >> 6, lane = tid & 63;
  int qd = lane >> 4, l15 = lane & 15;
  int wr = w >> 1, wc = w & 1;    // wr: 64-row half, wc: 32-col half

  // XCD swizzle: nwg = 16*32 = 512, %8==0.
  unsigned bid = blockIdx.y * 16u + blockIdx.x;
  unsigned swz = (bid & 7u) * 64u + (bid >> 3);
  int bx = (int)(swz % 16u);
  int by = (int)(swz / 16u);
  int row0 = by*128;
  int col0 = bx*64;

  int srow = tid >> 2;
  int scol = (tid & 3) * 8;
  const u16* ga0 = ab + (size_t)(row0 + srow)*E_DIM + scol;
  const u16* ga1 = ab + (size_t)(row0 + 64 + srow)*E_DIM + scol;
  const u16* gb0 = wob + (size_t)(col0 + srow)*E_DIM + scol;
  u16* lA0 = sA + tid*8;
  u16* lA1 = sA + 2048 + tid*8;
  u16* lB0 = sB + tid*8;

  f32x4 z = {0.f,0.f,0.f,0.f};
  f32x4 acc[4][2];
  for (int i=0;i<4;i++) for (int j=0;j<2;j++) acc[i][j] = z;

  const u16* pa = sA + (wr*64 + l15)*32 + qd*8;
  const u16* pb = sB + (wc*32 + l15)*32 + qd*8;

  for (int kk = 0; kk < E_DIM; kk += 32){
    gl_lds16(ga0 + kk, lA0);
    gl_lds16(ga1 + kk, lA1);
    gl_lds16(gb0 + kk, lB0);
    __syncthreads();
    bf16x8 a[4], bfr[2];
#pragma unroll
    for (int i=0;i<4;i++) a[i] = *(const bf16x8*)(pa + i*512);
#pragma unroll
    for (int j=0;j<2;j++) bfr[j] = *(const bf16x8*)(pb + j*512);
#pragma unroll
    for (int i=0;i<4;i++)
#pragma unroll
      for (int j=0;j<2;j++)
        acc[i][j] = __builtin_amdgcn_mfma_f32_16x16x32_bf16(a[i], bfr[j], acc[i][j], 0,0,0);
    __syncthreads();
  }

#pragma unroll
  for (int j=0;j<2;j++){
    int n = col0 + wc*32 + j*16 + l15;
    float bias = bo[n];
#pragma unroll
    for (int i=0;i<4;i++){
#pragma unroll
      for (int r=0;r<4;r++){
        int row = row0 + wr*64 + i*16 + qd*4 + r;
        out[(size_t)row*E_DIM + n] = acc[i][j][r] + bias;
      }
    }
  }
}

extern "C" void kernel_launch(void* const* d_in, const int* in_sizes, int n_in,
                              void* d_out, int out_size, void* d_ws, size_t ws_size,
                              hipStream_t stream) {
  const float* x    = (const float*)d_in[0];
  const void*  pm   = d_in[1];
  const float* abias= (const float*)d_in[2];
  const float* Wq   = (const float*)d_in[3];
  const float* bq   = (const float*)d_in[4];
  const float* Wk   = (const float*)d_in[5];
  const float* bk   = (const float*)d_in[6];
  const float* Wv   = (const float*)d_in[7];
  const float* bv   = (const float*)d_in[8];
  const float* Wo   = (const float*)d_in[9];
  const float* bo   = (const float*)d_in[10];
  float* out = (float*)d_out;

  char* ws = (char*)d_ws;
  u16* xb    = (u16*)(ws);                      // 8 MB  [4096][1024]
  u16* wqkvb = (u16*)(ws + (8u<<20));           // 6 MB  [3072][1024] (wq|wk|wv)
  u16* wob   = (u16*)(ws + (14u<<20));          // 2 MB  [1024][1024]
  u16* qb    = (u16*)(ws + (16u<<20));          // 8 MB  [b][h][t][d]
  u16* kb    = (u16*)(ws + (24u<<20));          // 8 MB  [b][h][t][d]
  u16* vtb   = (u16*)(ws + (32u<<20));          // 8 MB  [b][h][d][t]
  u16* attnb = (u16*)(ws + (40u<<20));          // 8 MB  [4096][1024]

  // converts
  {
    int n4x = (T_DIM*B_DIM*E_DIM)/4;            // 1048576
    convert_f32_bf16<<<dim3(n4x/256), 256, 0, stream>>>(x, xb, n4x);
    int n4w = (E_DIM*E_DIM)/4;                  // 262144
    convert_f32_bf16<<<dim3(n4w/256), 256, 0, stream>>>(Wq, wqkvb,                 n4w);
    convert_f32_bf16<<<dim3(n4w/256), 256, 0, stream>>>(Wk, wqkvb + (1u<<20),      n4w);
    convert_f32_bf16<<<dim3(n4w/256), 256, 0, stream>>>(Wv, wqkvb + (2u<<20),      n4w);
    convert_f32_bf16<<<dim3(n4w/256), 256, 0, stream>>>(Wo, wob,                   n4w);
  }

  gemm_qkv<<<dim3(3*E_DIM/128, NROWS/128), 256, 0, stream>>>(
      xb, wqkvb, bq, bk, bv, qb, kb, vtb);

  attn_kernel<<<dim3(T_DIM/64, B_DIM*H_DIM), 512, 0, stream>>>(
      qb, kb, vtb, abias, pm, attnb);

  gemm_out<<<dim3(E_DIM/64, NROWS/128), 256, 0, stream>>>(
      attnb, wob, bo, out);
}

// Round 4
// 857.480 us; speedup vs baseline: 2.3227x; 1.1130x over previous
//
#include <hip/hip_runtime.h>

#define E_DIM 1024
#define H_DIM 16
#define T_DIM 2048
#define B_DIM 2
#define HD_DIM 64
#define NROWS (T_DIM*B_DIM)   // 4096

typedef unsigned short u16;
typedef unsigned long long u64;
typedef __attribute__((ext_vector_type(8))) short bf16x8;
typedef __attribute__((ext_vector_type(4))) float f32x4;

__device__ __forceinline__ u16 f2bf(float f){
  unsigned int u = __float_as_uint(f);
  u = u + 0x7fffu + ((u>>16)&1u);      // round-to-nearest-even
  return (u16)(u>>16);
}

// async global->LDS, 16B per lane. Dest must be linear base + lane*16.
__device__ __forceinline__ void gl_lds16(const void* g, void* l){
  __builtin_amdgcn_global_load_lds(
      (const __attribute__((address_space(1))) void*)g,
      (__attribute__((address_space(3))) void*)l, 16, 0, 0);
}

// 16-lane butterfly reduction via DPP (pure VALU, no LDS pipe).
#define DPP_F(v, op, ctrl) \
  v = op(v, __int_as_float(__builtin_amdgcn_mov_dpp(__float_as_int(v), ctrl, 0xf, 0xf, true)))
__device__ __forceinline__ float fadd_(float a, float b){ return a + b; }

// ---------------- fp32 -> bf16 conversion (4 elems/thread) ----------------
__global__ __launch_bounds__(256) void convert_f32_bf16(
    const float* __restrict__ src, u16* __restrict__ dst, int n4)
{
  int i = blockIdx.x*256 + threadIdx.x;
  if (i < n4){
    float4 f = ((const float4*)src)[i];
    u64 pack =  (u64)f2bf(f.x)
             | ((u64)f2bf(f.y) << 16)
             | ((u64)f2bf(f.z) << 32)
             | ((u64)f2bf(f.w) << 48);
    ((u64*)dst)[i] = pack;
  }
}

// ---------------- fused QKV projection GEMM -------------------------------
__global__ __launch_bounds__(256) void gemm_qkv(
    const u16* __restrict__ xb, const u16* __restrict__ wb,
    const float* __restrict__ bq, const float* __restrict__ bk,
    const float* __restrict__ bv,
    u16* __restrict__ qb, u16* __restrict__ kb, u16* __restrict__ vtb)
{
  __shared__ u16 sA[128*32];
  __shared__ u16 sB[128*32];
  int tid = threadIdx.x;
  int w = tid >> 6, lane = tid & 63;
  int qd = lane >> 4, l15 = lane & 15;
  int wr = w >> 1, wc = w & 1;

  // XCD-aware bijective swizzle: nwg = 24*32 = 768, 768 % 8 == 0.
  unsigned bid = blockIdx.y * 24u + blockIdx.x;
  unsigned swz = (bid & 7u) * 96u + (bid >> 3);
  int bx = (int)(swz % 24u);
  int by = (int)(swz / 24u);
  int row0 = by*128;
  int col0 = bx*128;

  int srow = tid >> 2;
  int scol = (tid & 3) * 8;
  const u16* ga0 = xb + (size_t)(row0 + srow)*E_DIM + scol;
  const u16* ga1 = xb + (size_t)(row0 + 64 + srow)*E_DIM + scol;
  const u16* gb0 = wb + (size_t)(col0 + srow)*E_DIM + scol;
  const u16* gb1 = wb + (size_t)(col0 + 64 + srow)*E_DIM + scol;
  u16* lA0 = sA + tid*8;
  u16* lA1 = sA + 2048 + tid*8;
  u16* lB0 = sB + tid*8;
  u16* lB1 = sB + 2048 + tid*8;

  f32x4 z = {0.f,0.f,0.f,0.f};
  f32x4 acc[4][4];
  for (int i=0;i<4;i++) for (int j=0;j<4;j++) acc[i][j] = z;

  const u16* pa = sA + (wr*64 + l15)*32 + qd*8;
  const u16* pb = sB + (wc*64 + l15)*32 + qd*8;

  for (int kk = 0; kk < E_DIM; kk += 32){
    gl_lds16(ga0 + kk, lA0);
    gl_lds16(ga1 + kk, lA1);
    gl_lds16(gb0 + kk, lB0);
    gl_lds16(gb1 + kk, lB1);
    __syncthreads();
    bf16x8 a[4], bfr[4];
#pragma unroll
    for (int i=0;i<4;i++){
      a[i]   = *(const bf16x8*)(pa + i*512);
      bfr[i] = *(const bf16x8*)(pb + i*512);
    }
#pragma unroll
    for (int i=0;i<4;i++)
#pragma unroll
      for (int j=0;j<4;j++)
        acc[i][j] = __builtin_amdgcn_mfma_f32_16x16x32_bf16(a[i], bfr[j], acc[i][j], 0,0,0);
    __syncthreads();
  }

#pragma unroll
  for (int j=0;j<4;j++){
    int n = col0 + wc*64 + j*16 + l15;
    int p = n >> 10;          // 0=q 1=k 2=v
    int e = n & 1023;
    int hh = e >> 6, d = e & 63;
    float bias = (p==0) ? bq[e] : (p==1) ? bk[e] : bv[e];
#pragma unroll
    for (int i=0;i<4;i++){
#pragma unroll
      for (int r=0;r<4;r++){
        int row = row0 + wr*64 + i*16 + qd*4 + r;
        int t = row >> 1, b = row & 1;
        float val = acc[i][j][r] + bias;
        if (p == 0){
          val *= 0.125f;
          qb[((size_t)((b*H_DIM+hh)*T_DIM + t))*HD_DIM + d] = f2bf(val);
        } else if (p == 1){
          kb[((size_t)((b*H_DIM+hh)*T_DIM + t))*HD_DIM + d] = f2bf(val);
        } else {
          vtb[((size_t)((b*H_DIM+hh)*HD_DIM + d))*T_DIM + t] = f2bf(val);
        }
      }
    }
  }
}

// ---------------- flash attention ----------------------------------------
// One block = one (b,h) x 64 t-rows, 4 waves x 16 rows, s-step = 32.
// K/V/bias are LDS-staged per block via global_load_lds (shared across waves,
// fully coalesced, zero VGPR cost) with a 2-phase pipeline:
//   stage(next buf) -> compute(cur buf) -> vmcnt(0) -> s_barrier -> swap.
// HBM latency of the stage hides under the whole compute phase instead of
// per-wave register chains.  LDS 36 KB -> 4 blocks/CU.
__global__ __launch_bounds__(256, 4) void attn_kernel(
    const u16* __restrict__ qb, const u16* __restrict__ kb,
    const u16* __restrict__ vtb, const float* __restrict__ bias,
    const void* __restrict__ pmask, u16* __restrict__ attnb)
{
  __shared__ u16 kbuf[2][32*64];       // 8 KB  [s-row][d], 16B chunks XOR-swizzled by (row&7)
  __shared__ u16 vbuf[2][64*32];       // 8 KB  [d][s]
  __shared__ float bbuf[2][64*32];     // 16 KB [t][s] fp32, 4-float chunks XOR-swizzled by qd(row)
  __shared__ u16 p_lds[4][16][32];     // 4 KB
  __shared__ int s_bytemode;
  int tid = threadIdx.x;
  if (tid == 0) s_bytemode = 0;
  __syncthreads();
  {
    // detect mask dtype: int32 {0,1} has zero bytes at offset%4 != 0
    const unsigned char* pb_ = (const unsigned char*)pmask;
    unsigned char c = pb_[tid*4+1] | pb_[tid*4+2] | pb_[tid*4+3];
    if (c) s_bytemode = 1;    // benign same-value race
  }
  __syncthreads();
  int bytemode = s_bytemode;

  int w = tid >> 6, lane = tid & 63;
  int qd = lane >> 4, l15 = lane & 15;
  int bh = blockIdx.y;
  int b = bh >> 4;            // H=16
  int hh = bh & 15;
  int trow_blk = blockIdx.x*64;
  int trow0 = trow_blk + w*16;

  const u16* qh = qb + (size_t)bh * T_DIM * HD_DIM;
  const u16* kh = kb + (size_t)bh * T_DIM * HD_DIM;
  const u16* vh = vtb + (size_t)bh * HD_DIM * T_DIM;
  const float* biash = bias + (size_t)bh * T_DIM * T_DIM;
  const int* pmi = (const int*)pmask;
  const unsigned char* pmb = (const unsigned char*)pmask;

  int tq = trow0 + l15;
  bf16x8 aq0 = *(const bf16x8*)(qh + (size_t)tq*HD_DIM + qd*8);
  bf16x8 aq1 = *(const bf16x8*)(qh + (size_t)tq*HD_DIM + 32 + qd*8);

  f32x4 z = {0.f,0.f,0.f,0.f};
  f32x4 o[4]; for (int i=0;i<4;i++) o[i] = z;
  float m_r[4] = {-1e30f,-1e30f,-1e30f,-1e30f};
  float l_r[4] = {0.f,0.f,0.f,0.f};

  // ---- per-thread staging source offsets (constant across steps) ----
  // K tile: 32 rows x 64 d (bf16) = 4 KB; thread -> row tid/8, chunk tid%8.
  int krow = tid >> 3, kch = tid & 7;
  const u16* ksrc = kh + (size_t)krow*HD_DIM + ((kch ^ (krow&7)) << 3);
  // V tile: 64 d-rows x 32 s (bf16) = 4 KB; thread -> row tid/4, chunk tid%4.
  int vrow = tid >> 2, vch = tid & 3;
  const u16* vsrc = vh + (size_t)vrow*T_DIM + (vch << 3);
  // bias tile: 64 rows x 32 s (fp32) = 8 KB; slots tid and 256+tid.
  int br0 = tid >> 3, bc4 = tid & 7;
  int rq0 = (br0 >> 2) & 3;
  const float* bsrc0 = biash + (size_t)(trow_blk + br0)*T_DIM
                     + ((bc4 ^ ((rq0&1)<<2) ^ (rq0>>1)) << 2);
  int br1 = 32 + br0;
  int rq1 = (br1 >> 2) & 3;
  const float* bsrc1 = biash + (size_t)(trow_blk + br1)*T_DIM
                     + ((bc4 ^ ((rq1&1)<<2) ^ (rq1>>1)) << 2);

  // ---- compute-side LDS offsets ----
  int xk = l15 & 7;
  int kof00 = l15*64      + ((qd    ^ xk) << 3);
  int kof01 = l15*64      + (((4+qd)^ xk) << 3);
  int kof10 = (16+l15)*64 + ((qd    ^ xk) << 3);
  int kof11 = (16+l15)*64 + (((4+qd)^ xk) << 3);
  int bxor = ((qd&1)<<2) ^ (qd>>1);
  int bof0 = (((l15>>2)     ^ bxor) << 2) + (l15&3);   // col l15
  int bof1 = (((4+(l15>>2)) ^ bxor) << 2) + (l15&3);   // col 16+l15

  int cur = 0;
  // prologue: stage step 0, load step-0 masks
  gl_lds16(ksrc, &kbuf[0][tid*8]);
  gl_lds16(vsrc, &vbuf[0][tid*8]);
  gl_lds16(bsrc0, &bbuf[0][tid*4]);
  gl_lds16(bsrc1, &bbuf[0][1024 + tid*4]);
  bool msk0 = bytemode ? (pmb[b*T_DIM + l15] != 0)      : (pmi[b*T_DIM + l15] != 0);
  bool msk1 = bytemode ? (pmb[b*T_DIM + 16 + l15] != 0) : (pmi[b*T_DIM + 16 + l15] != 0);
  __asm__ __volatile__("s_waitcnt vmcnt(0)" ::: "memory");
  __builtin_amdgcn_s_barrier();
  __asm__ __volatile__("" ::: "memory");

  for (int s0 = 0; s0 < T_DIM; s0 += 32){
    // ---- stage next step into the other buffer (async, no VGPR cost) ----
    int sn = s0 + 32;
    if (sn < T_DIM){
      int nb = cur ^ 1;
      gl_lds16(ksrc + (size_t)sn*HD_DIM, &kbuf[nb][tid*8]);
      gl_lds16(vsrc + sn,                &vbuf[nb][tid*8]);
      gl_lds16(bsrc0 + sn,               &bbuf[nb][tid*4]);
      gl_lds16(bsrc1 + sn,               &bbuf[nb][1024 + tid*4]);
    } else sn = 0;
    bool nmsk0 = bytemode ? (pmb[b*T_DIM + sn + l15] != 0)      : (pmi[b*T_DIM + sn + l15] != 0);
    bool nmsk1 = bytemode ? (pmb[b*T_DIM + sn + 16 + l15] != 0) : (pmi[b*T_DIM + sn + 16 + l15] != 0);

    // ---- compute from buf[cur] ----
    const u16* kb_ = kbuf[cur];
    bf16x8 k00 = *(const bf16x8*)(kb_ + kof00);
    bf16x8 k01 = *(const bf16x8*)(kb_ + kof01);
    bf16x8 k10 = *(const bf16x8*)(kb_ + kof10);
    bf16x8 k11 = *(const bf16x8*)(kb_ + kof11);

    f32x4 sA = __builtin_amdgcn_mfma_f32_16x16x32_bf16(aq1, k01, z, 0,0,0);
    sA       = __builtin_amdgcn_mfma_f32_16x16x32_bf16(aq0, k00, sA, 0,0,0);
    f32x4 sB = __builtin_amdgcn_mfma_f32_16x16x32_bf16(aq1, k11, z, 0,0,0);
    sB       = __builtin_amdgcn_mfma_f32_16x16x32_bf16(aq0, k10, sB, 0,0,0);

    const float* bb_ = bbuf[cur];
#pragma unroll
    for (int r=0;r<4;r++){
      int brow = (w*16 + qd*4 + r) * 32;
      float v0 = (msk0 ? -1e-16f : sA[r]) + bb_[brow + bof0];
      float v1 = (msk1 ? -1e-16f : sB[r]) + bb_[brow + bof1];
      float tm = fmaxf(v0, v1);
      DPP_F(tm, fmaxf, 0xB1);
      DPP_F(tm, fmaxf, 0x4E);
      DPP_F(tm, fmaxf, 0x141);
      DPP_F(tm, fmaxf, 0x140);
      float mn = fmaxf(m_r[r], tm);
      float alpha = __expf(m_r[r] - mn);
      float p0 = __expf(v0 - mn);
      float p1 = __expf(v1 - mn);
      float rs = p0 + p1;
      DPP_F(rs, fadd_, 0xB1);
      DPP_F(rs, fadd_, 0x4E);
      DPP_F(rs, fadd_, 0x141);
      DPP_F(rs, fadd_, 0x140);
      l_r[r] = l_r[r]*alpha + rs;
      m_r[r] = mn;
      o[0][r] *= alpha; o[1][r] *= alpha; o[2][r] *= alpha; o[3][r] *= alpha;
      p_lds[w][qd*4+r][l15]      = f2bf(p0);
      p_lds[w][qd*4+r][16 + l15] = f2bf(p1);
    }
    // wave-local ordering of p_lds write->read; does NOT drain vmcnt.
    __asm__ __volatile__("s_waitcnt lgkmcnt(0)" ::: "memory");

    bf16x8 ap = *(const bf16x8*)(&p_lds[w][l15][qd*8]);
    const u16* vb_ = vbuf[cur];
#pragma unroll
    for (int dt=0; dt<4; dt++){
      bf16x8 bv = *(const bf16x8*)(vb_ + (dt*16 + l15)*32 + qd*8);
      o[dt] = __builtin_amdgcn_mfma_f32_16x16x32_bf16(ap, bv, o[dt], 0,0,0);
    }

    // ---- step boundary: wait staged data, swap buffers ----
    __asm__ __volatile__("s_waitcnt vmcnt(0)" ::: "memory");
    __builtin_amdgcn_s_barrier();
    __asm__ __volatile__("" ::: "memory");
    cur ^= 1;
    msk0 = nmsk0; msk1 = nmsk1;
  }

#pragma unroll
  for (int dt=0; dt<4; dt++){
#pragma unroll
    for (int r=0;r<4;r++){
      int t = trow0 + qd*4 + r;
      float val = o[dt][r] / l_r[r];
      attnb[(size_t)(t*B_DIM + b)*E_DIM + hh*HD_DIM + dt*16 + l15] = f2bf(val);
    }
  }
}

// ---------------- output projection GEMM ----------------------------------
// 128x64 tile (rows x cols) -> grid 16x32 = 512 blocks = 2/CU.
__global__ __launch_bounds__(256) void gemm_out(
    const u16* __restrict__ ab, const u16* __restrict__ wob,
    const float* __restrict__ bo, float* __restrict__ out)
{
  __shared__ u16 sA[128*32];   // 8 KB
  __shared__ u16 sB[64*32];    // 4 KB
  int tid = threadIdx.x;
  int w = tid >> 6, lane = tid & 63;
  int qd = lane >> 4, l15 = lane & 15;
  int wr = w >> 1, wc = w & 1;

  // XCD swizzle: nwg = 16*32 = 512, %8==0.
  unsigned bid = blockIdx.y * 16u + blockIdx.x;
  unsigned swz = (bid & 7u) * 64u + (bid >> 3);
  int bx = (int)(swz % 16u);
  int by = (int)(swz / 16u);
  int row0 = by*128;
  int col0 = bx*64;

  int srow = tid >> 2;
  int scol = (tid & 3) * 8;
  const u16* ga0 = ab + (size_t)(row0 + srow)*E_DIM + scol;
  const u16* ga1 = ab + (size_t)(row0 + 64 + srow)*E_DIM + scol;
  const u16* gb0 = wob + (size_t)(col0 + srow)*E_DIM + scol;
  u16* lA0 = sA + tid*8;
  u16* lA1 = sA + 2048 + tid*8;
  u16* lB0 = sB + tid*8;

  f32x4 z = {0.f,0.f,0.f,0.f};
  f32x4 acc[4][2];
  for (int i=0;i<4;i++) for (int j=0;j<2;j++) acc[i][j] = z;

  const u16* pa = sA + (wr*64 + l15)*32 + qd*8;
  const u16* pb = sB + (wc*32 + l15)*32 + qd*8;

  for (int kk = 0; kk < E_DIM; kk += 32){
    gl_lds16(ga0 + kk, lA0);
    gl_lds16(ga1 + kk, lA1);
    gl_lds16(gb0 + kk, lB0);
    __syncthreads();
    bf16x8 a[4], bfr[2];
#pragma unroll
    for (int i=0;i<4;i++) a[i] = *(const bf16x8*)(pa + i*512);
#pragma unroll
    for (int j=0;j<2;j++) bfr[j] = *(const bf16x8*)(pb + j*512);
#pragma unroll
    for (int i=0;i<4;i++)
#pragma unroll
      for (int j=0;j<2;j++)
        acc[i][j] = __builtin_amdgcn_mfma_f32_16x16x32_bf16(a[i], bfr[j], acc[i][j], 0,0,0);
    __syncthreads();
  }

#pragma unroll
  for (int j=0;j<2;j++){
    int n = col0 + wc*32 + j*16 + l15;
    float bias = bo[n];
#pragma unroll
    for (int i=0;i<4;i++){
#pragma unroll
      for (int r=0;r<4;r++){
        int row = row0 + wr*64 + i*16 + qd*4 + r;
        out[(size_t)row*E_DIM + n] = acc[i][j][r] + bias;
      }
    }
  }
}

extern "C" void kernel_launch(void* const* d_in, const int* in_sizes, int n_in,
                              void* d_out, int out_size, void* d_ws, size_t ws_size,
                              hipStream_t stream) {
  const float* x    = (const float*)d_in[0];
  const void*  pm   = d_in[1];
  const float* abias= (const float*)d_in[2];
  const float* Wq   = (const float*)d_in[3];
  const float* bq   = (const float*)d_in[4];
  const float* Wk   = (const float*)d_in[5];
  const float* bk   = (const float*)d_in[6];
  const float* Wv   = (const float*)d_in[7];
  const float* bv   = (const float*)d_in[8];
  const float* Wo   = (const float*)d_in[9];
  const float* bo   = (const float*)d_in[10];
  float* out = (float*)d_out;

  char* ws = (char*)d_ws;
  u16* xb    = (u16*)(ws);                      // 8 MB  [4096][1024]
  u16* wqkvb = (u16*)(ws + (8u<<20));           // 6 MB  [3072][1024] (wq|wk|wv)
  u16* wob   = (u16*)(ws + (14u<<20));          // 2 MB  [1024][1024]
  u16* qb    = (u16*)(ws + (16u<<20));          // 8 MB  [b][h][t][d]
  u16* kb    = (u16*)(ws + (24u<<20));          // 8 MB  [b][h][t][d]
  u16* vtb   = (u16*)(ws + (32u<<20));          // 8 MB  [b][h][d][t]
  u16* attnb = (u16*)(ws + (40u<<20));          // 8 MB  [4096][1024]

  // converts
  {
    int n4x = (T_DIM*B_DIM*E_DIM)/4;            // 1048576
    convert_f32_bf16<<<dim3(n4x/256), 256, 0, stream>>>(x, xb, n4x);
    int n4w = (E_DIM*E_DIM)/4;                  // 262144
    convert_f32_bf16<<<dim3(n4w/256), 256, 0, stream>>>(Wq, wqkvb,                 n4w);
    convert_f32_bf16<<<dim3(n4w/256), 256, 0, stream>>>(Wk, wqkvb + (1u<<20),      n4w);
    convert_f32_bf16<<<dim3(n4w/256), 256, 0, stream>>>(Wv, wqkvb + (2u<<20),      n4w);
    convert_f32_bf16<<<dim3(n4w/256), 256, 0, stream>>>(Wo, wob,                   n4w);
  }

  gemm_qkv<<<dim3(3*E_DIM/128, NROWS/128), 256, 0, stream>>>(
      xb, wqkvb, bq, bk, bv, qb, kb, vtb);

  attn_kernel<<<dim3(T_DIM/64, B_DIM*H_DIM), 256, 0, stream>>>(
      qb, kb, vtb, abias, pm, attnb);

  gemm_out<<<dim3(E_DIM/64, NROWS/128), 256, 0, stream>>>(
      attnb, wob, bo, out);
}